// Round 6
// baseline (407.285 us; speedup 1.0000x reference)
//
#include <hip/hip_runtime.h>
#include <hip/hip_bf16.h>

using bf16 = __hip_bfloat16;
typedef __attribute__((ext_vector_type(8))) short short8;
typedef __attribute__((ext_vector_type(4))) float f32x4;

#define NLAY 2
#define NN1 8
#define NN2 8
#define PP 1024
#define DD 768
#define MROWS (NN1*PP)   // 8192
#define BM 256
#define BN 256
#define BK 64
#define NKT (DD/BK)      // 12 K-tiles
#define NCT (MROWS/BN)   // 32 col tiles

// ---------------- normalize rows + convert to bf16 (both inputs fused) ----
__global__ __launch_bounds__(256) void normalize_kernel(
    const float* __restrict__ in0, const float* __restrict__ in1,
    bf16* __restrict__ out0, bf16* __restrict__ out1) {
  int row  = blockIdx.x * 4 + (threadIdx.x >> 6);
  int lane = threadIdx.x & 63;
  const int half = NLAY * MROWS;
  const float* src;
  bf16* dst;
  if (row < half) { src = in0 + (size_t)row * DD;          dst = out0 + (size_t)row * DD; }
  else            { src = in1 + (size_t)(row - half) * DD; dst = out1 + (size_t)(row - half) * DD; }
  float4 v[3];
  float ss = 0.f;
#pragma unroll
  for (int i = 0; i < 3; i++) {
    v[i] = *reinterpret_cast<const float4*>(src + lane * 4 + i * 256);
    ss += v[i].x * v[i].x + v[i].y * v[i].y + v[i].z * v[i].z + v[i].w * v[i].w;
  }
#pragma unroll
  for (int off = 1; off < 64; off <<= 1) ss += __shfl_xor(ss, off);
  float rn = rsqrtf(ss);
#pragma unroll
  for (int i = 0; i < 3; i++) {
    bf16 tmp[4];
    tmp[0] = __float2bfloat16(v[i].x * rn);
    tmp[1] = __float2bfloat16(v[i].y * rn);
    tmp[2] = __float2bfloat16(v[i].z * rn);
    tmp[3] = __float2bfloat16(v[i].w * rn);
    *reinterpret_cast<uint2*>(dst + lane * 4 + i * 256) =
        *reinterpret_cast<const uint2*>(tmp);
  }
}

// ---------------- 256x256 GEMM, 16x16x32 MFMA, 4 phases / 2 K-tiles --------
// 512 threads = 8 waves (wr = wave>>2 row half, wc = wave&3 col stripe).
// Phase = [barrier][ds_reads][stage-issue][MFMA x32][counted vmcnt].
// NO explicit lgkmcnt(0): compiler emits fine-grained per-MFMA lgkm waits so
// ds_reads of later fragments overlap MFMAs of earlier ones; reads are fully
// drained before the next barrier via MFMA data dependence (WAR-safe).
// B frags read at qm0 and held in regs through qm1.
// LDS: As/Bs [2 dbuf][2 half][128*64] bf16 = 128 KiB. Swizzle: 16B slot s of
// row r stored at s^(r&7); global source pre-swizzled, reads apply same XOR
// (16-row x 4-slot-group read pattern -> 2-way bank aliasing = free).

__device__ __forceinline__ short8 ld_frag(const bf16* h, int r, int slot) {
  return *reinterpret_cast<const short8*>(h + r * 64 + (((slot) ^ (r & 7)) << 3));
}

#define STAGE(Gbase, Lds) do {                                                  \
  _Pragma("unroll")                                                             \
  for (int i_ = 0; i_ < 2; i_++) {                                              \
    int u_ = i_ * 512 + t;                                                      \
    int r_ = u_ >> 3, s_ = u_ & 7;                                              \
    int sc_ = ((s_ ^ (r_ & 7)) << 3);                                           \
    __builtin_amdgcn_global_load_lds(                                           \
      (const __attribute__((address_space(1))) void*)((Gbase) + (size_t)r_ * DD + sc_), \
      (__attribute__((address_space(3))) void*)((Lds) + u_ * 8), 16, 0, 0);     \
  } } while (0)

#define VM2 asm volatile("s_waitcnt vmcnt(2)" ::: "memory")
#define VM0 asm volatile("s_waitcnt vmcnt(0)" ::: "memory")

#define LOAD_A(buf, qm)                                                         \
  _Pragma("unroll") for (int m_ = 0; m_ < 4; m_++)                              \
  _Pragma("unroll") for (int ks_ = 0; ks_ < 2; ks_++)                           \
    af_[m_][ks_] = ld_frag(&As[buf][qm][0], wr * 64 + m_ * 16 + rrow, ks_ * 4 + krow);

#define LOAD_B(buf)                                                             \
  _Pragma("unroll") for (int q_ = 0; q_ < 2; q_++)                              \
  _Pragma("unroll") for (int n_ = 0; n_ < 2; n_++)                              \
  _Pragma("unroll") for (int ks_ = 0; ks_ < 2; ks_++)                           \
    bf_[q_][n_][ks_] = ld_frag(&Bs[buf][q_][0], wc * 32 + n_ * 16 + rrow, ks_ * 4 + krow);

#define PHASEQ(buf, qm, LDB, STG, VMC) do {                                     \
  __builtin_amdgcn_s_barrier();                                                 \
  LOAD_A(buf, qm);                                                              \
  LDB;                                                                          \
  STG;                                                                          \
  __builtin_amdgcn_s_setprio(1);                                                \
  _Pragma("unroll") for (int q_ = 0; q_ < 2; q_++)                              \
  _Pragma("unroll") for (int n_ = 0; n_ < 2; n_++)                              \
  _Pragma("unroll") for (int m_ = 0; m_ < 4; m_++)                              \
  _Pragma("unroll") for (int ks_ = 0; ks_ < 2; ks_++)                           \
    acc[(qm) * 4 + m_][q_ * 2 + n_] = __builtin_amdgcn_mfma_f32_16x16x32_bf16(  \
        af_[m_][ks_], bf_[q_][n_][ks_], acc[(qm) * 4 + m_][q_ * 2 + n_], 0, 0, 0); \
  __builtin_amdgcn_s_setprio(0);                                                \
  VMC;                                                                          \
} while (0)

__global__ __launch_bounds__(512, 2) void gemm_max_kernel(
    const bf16* __restrict__ A, const bf16* __restrict__ Bm,
    float* __restrict__ partials) {
  __shared__ bf16 As[2][2][128 * 64];
  __shared__ bf16 Bs[2][2][128 * 64];
  __shared__ float red[4][256];

  // XCD-aware swizzle: xcd = id&7 owns (layer, 8-tiler band); consecutive
  // dispatch rounds within a chunk cover 8 tiler x 4 tilec (~4.7MB in L2).
  const int id  = blockIdx.x;
  const int xcd = id & 7, p = id >> 3;
  const int l     = xcd >> 2;
  const int q     = p & 31, rnd = p >> 5;
  const int tiler = (xcd & 3) * 8 + (q & 7);
  const int tilec = rnd * 4 + (q >> 3);

  const bf16* Ab = A  + ((size_t)l * MROWS + (size_t)tiler * BM) * DD;
  const bf16* Bb = Bm + ((size_t)l * MROWS + (size_t)tilec * BN) * DD;

  const int t    = threadIdx.x;
  const int lane = t & 63;
  const int wave = t >> 6;
  const int wr   = wave >> 2;   // 0..1
  const int wc   = wave & 3;    // 0..3
  const int rrow = lane & 15;
  const int krow = lane >> 4;

  f32x4 acc[8][4];
#pragma unroll
  for (int m = 0; m < 8; m++)
#pragma unroll
    for (int n = 0; n < 4; n++) acc[m][n] = (f32x4){0.f, 0.f, 0.f, 0.f};

  // prologue: tile0 (4 units) -> buf0, As10(tile1) -> buf1
  STAGE(Ab,                      &As[0][0][0]);
  STAGE(Ab + (size_t)128 * DD,   &As[0][1][0]);
  STAGE(Bb,                      &Bs[0][0][0]);
  STAGE(Bb + (size_t)128 * DD,   &Bs[0][1][0]);
  STAGE(Ab + BK,                 &As[1][0][0]);
  VM2;

  for (int i = 0; i < NKT / 2; i++) {
    const int O = 2 * i + 1, E2 = 2 * i + 2, O2 = 2 * i + 3;
    short8 af_[4][2], bf_[2][2][2];
    // P1: buf0 qm0; stage odd tile's As11, Bs10, Bs11
    PHASEQ(0, 0, LOAD_B(0),
      { STAGE(Ab + (size_t)128 * DD + (size_t)O * BK, &As[1][1][0]);
        STAGE(Bb + (size_t)O * BK,                    &Bs[1][0][0]);
        STAGE(Bb + (size_t)128 * DD + (size_t)O * BK, &Bs[1][1][0]); }, (void)0);
    // P2: buf0 qm1 (B held); stage As00(E+2); counted vmcnt
    PHASEQ(0, 1, (void)0,
      if (E2 < NKT) STAGE(Ab + (size_t)E2 * BK, &As[0][0][0]),
      if (E2 < NKT) { VM2; } else { VM0; });
    // P3: buf1 qm0; stage As01, Bs00, Bs01 (E+2)
    PHASEQ(1, 0, LOAD_B(1),
      if (E2 < NKT) { STAGE(Ab + (size_t)128 * DD + (size_t)E2 * BK, &As[0][1][0]);
                      STAGE(Bb + (size_t)E2 * BK,                    &Bs[0][0][0]);
                      STAGE(Bb + (size_t)128 * DD + (size_t)E2 * BK, &Bs[0][1][0]); }, (void)0);
    // P4: buf1 qm1 (B held); stage As10(O+2); counted vmcnt
    PHASEQ(1, 1, (void)0,
      if (O2 < NKT) STAGE(Ab + (size_t)O2 * BK, &As[1][0][0]),
      if (O2 < NKT) { VM2; });
  }

  // epilogue: per-row max over this block's 256 cols.
  // C/D frag (16x16): col = lane&15, row = (lane>>4)*4 + j
#pragma unroll
  for (int m = 0; m < 8; m++) {
#pragma unroll
    for (int j = 0; j < 4; j++) {
      float v = acc[m][0][j];
      v = fmaxf(v, acc[m][1][j]);
      v = fmaxf(v, acc[m][2][j]);
      v = fmaxf(v, acc[m][3][j]);
#pragma unroll
      for (int off = 1; off < 16; off <<= 1) v = fmaxf(v, __shfl_xor(v, off));
      if (rrow == 0) {
        int row = (m >> 2) * 128 + wr * 64 + (m & 3) * 16 + krow * 4 + j;
        red[wc][row] = v;
      }
    }
  }
  __syncthreads();
  if (t < 256) {
    float v = fmaxf(fmaxf(red[0][t], red[1][t]), fmaxf(red[2][t], red[3][t]));
    partials[((size_t)l * MROWS + (size_t)tiler * BM + t) * NCT + tilec] = v;
  }
}

// ------- reduce: maxdot -> sp -> scores + spatch; fused bilinear upsample --
// one block per n1 (8 blocks), 1024 threads
__global__ __launch_bounds__(1024) void reduce_upsample_kernel(
    const float* __restrict__ partials, const float* __restrict__ mask,
    float* __restrict__ scores, float* __restrict__ outpix) {
  const int n1 = blockIdx.x;
  const int p  = threadIdx.x;
  const int row = n1 * PP + p;
  const float mk = mask[row];

  __shared__ float sp_s[PP];   // spatch row [32][32]

  float sp[16];
  float ssum = 0.f;
#pragma unroll
  for (int l = 0; l < NLAY; l++) {
    const float* pr = partials + ((size_t)l * MROWS + row) * NCT;
#pragma unroll
    for (int n2 = 0; n2 < NN2; n2++) {
      float4 v4 = *reinterpret_cast<const float4*>(pr + n2 * 4);
      float md = fmaxf(fmaxf(v4.x, v4.y), fmaxf(v4.z, v4.w));
      float d2 = fmaxf(2.f - 2.f * md, 1e-12f);
      float s  = 0.5f * sqrtf(d2) * mk;
      sp[l * 8 + n2] = s;
      ssum += s;
    }
  }
  sp_s[p] = ssum * (1.f / 16.f);

  __shared__ float wred[16][16];
  __shared__ float sres[16];
  const int lane = p & 63;
  const int wave = p >> 6;
#pragma unroll
  for (int v = 0; v < 16; v++) {
    float x = sp[v];
#pragma unroll
    for (int off = 1; off < 64; off <<= 1) x = fmaxf(x, __shfl_xor(x, off));
    if (lane == 0) wred[wave][v] = x;
  }
  __syncthreads();
  if (p < 16) {
    float x = wred[0][p];
#pragma unroll
    for (int w = 1; w < 16; w++) x = fmaxf(x, wred[w][p]);
    sres[p] = x;
  }
  __syncthreads();
  if (p == 0) {
    float s = 0.f;
#pragma unroll
    for (int v = 0; v < 16; v++) s += sres[v];
    scores[n1] = s * (1.f / 16.f);
  }

  // bilinear 16x upsample from sp_s[32][32] -> outpix[n1][512][512]
  float* dst = outpix + (size_t)n1 * 512 * 512;
#pragma unroll 1
  for (int it = 0; it < 64; it++) {
    int idx4 = it * 1024 + p;          // float4 index
    int x0i  = (idx4 & 127) * 4;       // first x of the 4
    int y    = idx4 >> 7;
    float sy = (y + 0.5f) * 0.0625f - 0.5f;
    int yy0 = (int)floorf(sy); float wy = sy - (float)yy0;
    int yy1 = min(yy0 + 1, 31); yy0 = max(yy0, 0);
    const float* r0 = sp_s + yy0 * 32;
    const float* r1 = sp_s + yy1 * 32;
    float4 o;
#pragma unroll
    for (int k = 0; k < 4; k++) {
      int x = x0i + k;
      float sx = (x + 0.5f) * 0.0625f - 0.5f;
      int xx0 = (int)floorf(sx); float wx = sx - (float)xx0;
      int xx1 = min(xx0 + 1, 31); xx0 = max(xx0, 0);
      float v0 = (1.f - wx) * r0[xx0] + wx * r0[xx1];
      float v1 = (1.f - wx) * r1[xx0] + wx * r1[xx1];
      ((float*)&o)[k] = (1.f - wy) * v0 + wy * v1;
    }
    *reinterpret_cast<float4*>(dst + idx4 * 4) = o;
  }
}

extern "C" void kernel_launch(void* const* d_in, const int* in_sizes, int n_in,
                              void* d_out, int out_size, void* d_ws, size_t ws_size,
                              hipStream_t stream) {
  const float* feats  = (const float*)d_in[0];
  const float* nfeats = (const float*)d_in[1];
  const float* mask   = (const float*)d_in[2];
  float* out = (float*)d_out;

  bf16* Abf = (bf16*)d_ws;                                     // 2*8192*768 bf16
  bf16* Bbf = Abf + (size_t)NLAY * MROWS * DD;                 // same size
  float* partials = (float*)(Bbf + (size_t)NLAY * MROWS * DD); // [2][8192][32] f32

  normalize_kernel<<<(2 * NLAY * MROWS) / 4, 256, 0, stream>>>(feats, nfeats, Abf, Bbf);

  gemm_max_kernel<<<NCT * (MROWS / BM) * NLAY, 512, 0, stream>>>(Abf, Bbf, partials);

  reduce_upsample_kernel<<<NN1, 1024, 0, stream>>>(partials, mask, out, out + 8);
}

// Round 7
// 355.745 us; speedup vs baseline: 1.1449x; 1.1449x over previous
//
#include <hip/hip_runtime.h>
#include <hip/hip_bf16.h>

using bf16 = __hip_bfloat16;
typedef __attribute__((ext_vector_type(8))) short short8;
typedef __attribute__((ext_vector_type(4))) float f32x4;

#define NLAY 2
#define NN1 8
#define NN2 8
#define PP 1024
#define DD 768
#define MROWS (NN1*PP)   // 8192
#define BM 256
#define BN 256
#define BK 64
#define NKT (DD/BK)      // 12 K-tiles
#define NCT (MROWS/BN)   // 32 col tiles

// ---------------- normalize rows + convert to bf16 (both inputs fused) ----
__global__ __launch_bounds__(256) void normalize_kernel(
    const float* __restrict__ in0, const float* __restrict__ in1,
    bf16* __restrict__ out0, bf16* __restrict__ out1) {
  int row  = blockIdx.x * 4 + (threadIdx.x >> 6);
  int lane = threadIdx.x & 63;
  const int half = NLAY * MROWS;
  const float* src;
  bf16* dst;
  if (row < half) { src = in0 + (size_t)row * DD;          dst = out0 + (size_t)row * DD; }
  else            { src = in1 + (size_t)(row - half) * DD; dst = out1 + (size_t)(row - half) * DD; }
  float4 v[3];
  float ss = 0.f;
#pragma unroll
  for (int i = 0; i < 3; i++) {
    v[i] = *reinterpret_cast<const float4*>(src + lane * 4 + i * 256);
    ss += v[i].x * v[i].x + v[i].y * v[i].y + v[i].z * v[i].z + v[i].w * v[i].w;
  }
#pragma unroll
  for (int off = 1; off < 64; off <<= 1) ss += __shfl_xor(ss, off);
  float rn = rsqrtf(ss);
#pragma unroll
  for (int i = 0; i < 3; i++) {
    bf16 tmp[4];
    tmp[0] = __float2bfloat16(v[i].x * rn);
    tmp[1] = __float2bfloat16(v[i].y * rn);
    tmp[2] = __float2bfloat16(v[i].z * rn);
    tmp[3] = __float2bfloat16(v[i].w * rn);
    *reinterpret_cast<uint2*>(dst + lane * 4 + i * 256) =
        *reinterpret_cast<const uint2*>(tmp);
  }
}

// ---------------- 256x256 GEMM, m201 8-phase schedule, fused row-max -------
// 512 threads = 8 waves (wr = wave>>2 row half, wc = wave&3 col stripe).
// Phase = one C-quadrant (mh,bh) x K=64: [ds_reads][1-unit stage][barrier]
// [lgkmcnt(0)][setprio(1) 16 MFMA setprio(0)][vmcnt@ph3/ph7][barrier].
// A half read at ph(mh,0), held 2 phases; B halves read ph0/ph1, held 4.
// Stage slots (iter i, E=2i buf0, O=2i+1 buf1, E2=2i+2, O2=2i+3):
//   ph0:B[O]h1->Bs11  ph1:A[E2]h0->As00  ph2:B[E2]h0->Bs00  ph3:A[E2]h1->As01
//   ph4:B[E2]h1->Bs01 ph5:A[O2]h0->As10  ph6:B[O2]h0->Bs10  ph7:A[O2]h1->As11
// vmcnt(6) at ph3/ph7 (3 half-tile units in flight); vmcnt(0) tail last iter.
// LDS: As/Bs [2 dbuf][2 half][128*64] bf16 = 128 KiB. Swizzle: 16B slot s of
// row r stored at s^(r&7); global source pre-swizzled, reads apply same XOR
// (16-row x 4-slot-group read pattern -> 2-way bank aliasing = free).

__device__ __forceinline__ short8 ld_frag(const bf16* h, int r, int slot) {
  return *reinterpret_cast<const short8*>(h + r * 64 + (((slot) ^ (r & 7)) << 3));
}

#define STAGE(Gbase, Lds) do {                                                  \
  _Pragma("unroll")                                                             \
  for (int i_ = 0; i_ < 2; i_++) {                                              \
    int u_ = i_ * 512 + t;                                                      \
    int r_ = u_ >> 3, s_ = u_ & 7;                                              \
    int sc_ = ((s_ ^ (r_ & 7)) << 3);                                           \
    __builtin_amdgcn_global_load_lds(                                           \
      (const __attribute__((address_space(1))) void*)((Gbase) + (size_t)r_ * DD + sc_), \
      (__attribute__((address_space(3))) void*)((Lds) + u_ * 8), 16, 0, 0);     \
  } } while (0)

#define VM6 asm volatile("s_waitcnt vmcnt(6)" ::: "memory")
#define VM0 asm volatile("s_waitcnt vmcnt(0)" ::: "memory")

#define LOAD_A(buf, mh)                                                         \
  _Pragma("unroll") for (int m_ = 0; m_ < 4; m_++)                              \
  _Pragma("unroll") for (int ks_ = 0; ks_ < 2; ks_++)                           \
    af_[m_][ks_] = ld_frag(&As[buf][mh][0], wr * 64 + m_ * 16 + rrow, ks_ * 4 + krow);

#define LOAD_BH(buf, h)                                                         \
  _Pragma("unroll") for (int n_ = 0; n_ < 2; n_++)                              \
  _Pragma("unroll") for (int ks_ = 0; ks_ < 2; ks_++)                           \
    bf_[h][n_][ks_] = ld_frag(&Bs[buf][h][0], wc * 32 + n_ * 16 + rrow, ks_ * 4 + krow);

#define PH(mh, bh, RDS, STG, VMC) do {                                          \
  RDS;                                                                          \
  STG;                                                                          \
  __builtin_amdgcn_s_barrier();                                                 \
  asm volatile("s_waitcnt lgkmcnt(0)" ::: "memory");                            \
  __builtin_amdgcn_sched_barrier(0);                                            \
  __builtin_amdgcn_s_setprio(1);                                                \
  _Pragma("unroll") for (int n_ = 0; n_ < 2; n_++)                              \
  _Pragma("unroll") for (int m_ = 0; m_ < 4; m_++)                              \
  _Pragma("unroll") for (int ks_ = 0; ks_ < 2; ks_++)                           \
    acc[(mh) * 4 + m_][(bh) * 2 + n_] = __builtin_amdgcn_mfma_f32_16x16x32_bf16( \
        af_[m_][ks_], bf_[bh][n_][ks_], acc[(mh) * 4 + m_][(bh) * 2 + n_], 0, 0, 0); \
  __builtin_amdgcn_s_setprio(0);                                                \
  VMC;                                                                          \
  __builtin_amdgcn_s_barrier();                                                 \
} while (0)

__global__ __launch_bounds__(512, 2) void gemm_max_kernel(
    const bf16* __restrict__ A, const bf16* __restrict__ Bm,
    float* __restrict__ partials) {
  __shared__ bf16 As[2][2][128 * 64];
  __shared__ bf16 Bs[2][2][128 * 64];
  __shared__ float red[4][256];

  // XCD-aware swizzle: xcd = id&7 owns (layer, 8-tiler band); consecutive
  // dispatch rounds within a chunk cover 8 tiler x 4 tilec (~4.7MB in L2).
  const int id  = blockIdx.x;
  const int xcd = id & 7, p = id >> 3;
  const int l     = xcd >> 2;
  const int q     = p & 31, rnd = p >> 5;
  const int tiler = (xcd & 3) * 8 + (q & 7);
  const int tilec = rnd * 4 + (q >> 3);

  const bf16* Ab = A  + ((size_t)l * MROWS + (size_t)tiler * BM) * DD;
  const bf16* Bb = Bm + ((size_t)l * MROWS + (size_t)tilec * BN) * DD;

  const int t    = threadIdx.x;
  const int lane = t & 63;
  const int wave = t >> 6;
  const int wr   = wave >> 2;   // 0..1
  const int wc   = wave & 3;    // 0..3
  const int rrow = lane & 15;
  const int krow = lane >> 4;

  f32x4 acc[8][4];
#pragma unroll
  for (int m = 0; m < 8; m++)
#pragma unroll
    for (int n = 0; n < 4; n++) acc[m][n] = (f32x4){0.f, 0.f, 0.f, 0.f};

  // prologue: tile0 all 4 units -> buf0; tile1 A-h0, B-h0, A-h1 -> buf1.
  STAGE(Ab,                           &As[0][0][0]);
  STAGE(Bb,                           &Bs[0][0][0]);
  STAGE(Ab + (size_t)128 * DD,        &As[0][1][0]);
  STAGE(Bb + (size_t)128 * DD,        &Bs[0][1][0]);
  STAGE(Ab + BK,                      &As[1][0][0]);
  STAGE(Bb + BK,                      &Bs[1][0][0]);
  STAGE(Ab + (size_t)128 * DD + BK,   &As[1][1][0]);
  VM6;
  __builtin_amdgcn_s_barrier();

  for (int i = 0; i < NKT / 2; i++) {
    const int O = 2 * i + 1, E2 = 2 * i + 2, O2 = 2 * i + 3;
    short8 af_[4][2], bf_[2][2][2];
    // ---- tile E (buf0) ----
    PH(0, 0, { LOAD_A(0, 0); LOAD_BH(0, 0); },
       STAGE(Bb + (size_t)128 * DD + (size_t)O * BK, &Bs[1][1][0]), (void)0);
    PH(0, 1, LOAD_BH(0, 1),
       if (E2 < NKT) STAGE(Ab + (size_t)E2 * BK, &As[0][0][0]), (void)0);
    PH(1, 0, LOAD_A(0, 1),
       if (E2 < NKT) STAGE(Bb + (size_t)E2 * BK, &Bs[0][0][0]), (void)0);
    PH(1, 1, (void)0,
       if (E2 < NKT) STAGE(Ab + (size_t)128 * DD + (size_t)E2 * BK, &As[0][1][0]),
       if (E2 < NKT) { VM6; } else { VM0; });
    // ---- tile O (buf1) ----
    PH(0, 0, { LOAD_A(1, 0); LOAD_BH(1, 0); },
       if (E2 < NKT) STAGE(Bb + (size_t)128 * DD + (size_t)E2 * BK, &Bs[0][1][0]), (void)0);
    PH(0, 1, LOAD_BH(1, 1),
       if (O2 < NKT) STAGE(Ab + (size_t)O2 * BK, &As[1][0][0]), (void)0);
    PH(1, 0, LOAD_A(1, 1),
       if (O2 < NKT) STAGE(Bb + (size_t)O2 * BK, &Bs[1][0][0]), (void)0);
    PH(1, 1, (void)0,
       if (O2 < NKT) STAGE(Ab + (size_t)128 * DD + (size_t)O2 * BK, &As[1][1][0]),
       if (O2 < NKT) { VM6; });
  }

  // epilogue: per-row max over this block's 256 cols.
  // C/D frag (16x16): col = lane&15, row = (lane>>4)*4 + j
#pragma unroll
  for (int m = 0; m < 8; m++) {
#pragma unroll
    for (int j = 0; j < 4; j++) {
      float v = acc[m][0][j];
      v = fmaxf(v, acc[m][1][j]);
      v = fmaxf(v, acc[m][2][j]);
      v = fmaxf(v, acc[m][3][j]);
#pragma unroll
      for (int off = 1; off < 16; off <<= 1) v = fmaxf(v, __shfl_xor(v, off));
      if (rrow == 0) {
        int row = (m >> 2) * 128 + wr * 64 + (m & 3) * 16 + krow * 4 + j;
        red[wc][row] = v;
      }
    }
  }
  __syncthreads();
  if (t < 256) {
    float v = fmaxf(fmaxf(red[0][t], red[1][t]), fmaxf(red[2][t], red[3][t]));
    // transposed layout: [l][tilec][row] -> coalesced write AND coalesced
    // reduce-kernel read
    partials[((size_t)l * NCT + tilec) * MROWS + (size_t)tiler * BM + t] = v;
  }
}

// ---------------- reduce: maxdot -> sp -> scores + spatch ------------------
// one block per n1 (8 blocks), 1024 threads; partials transposed [l][tc][row]
__global__ __launch_bounds__(1024) void reduce_kernel(
    const float* __restrict__ partials, const float* __restrict__ mask,
    float* __restrict__ scores, float* __restrict__ spatch) {
  const int n1 = blockIdx.x;
  const int p  = threadIdx.x;
  const int row = n1 * PP + p;
  const float mk = mask[row];

  float sp[16];
  float ssum = 0.f;
#pragma unroll
  for (int l = 0; l < NLAY; l++) {
#pragma unroll
    for (int n2 = 0; n2 < NN2; n2++) {
      const float* pr = partials + ((size_t)l * NCT + n2 * 4) * MROWS + row;
      float md = pr[0];
#pragma unroll
      for (int tt = 1; tt < 4; tt++) md = fmaxf(md, pr[(size_t)tt * MROWS]);
      float d2 = fmaxf(2.f - 2.f * md, 1e-12f);
      float s  = 0.5f * sqrtf(d2) * mk;
      sp[l * 8 + n2] = s;
      ssum += s;
    }
  }
  spatch[row] = ssum * (1.f / 16.f);

  __shared__ float wred[16][16];
  __shared__ float sres[16];
  const int lane = p & 63;
  const int wave = p >> 6;
#pragma unroll
  for (int v = 0; v < 16; v++) {
    float x = sp[v];
#pragma unroll
    for (int off = 1; off < 64; off <<= 1) x = fmaxf(x, __shfl_xor(x, off));
    if (lane == 0) wred[wave][v] = x;
  }
  __syncthreads();
  if (p < 16) {
    float x = wred[0][p];
#pragma unroll
    for (int w = 1; w < 16; w++) x = fmaxf(x, wred[w][p]);
    sres[p] = x;
  }
  __syncthreads();
  if (p == 0) {
    float s = 0.f;
#pragma unroll
    for (int v = 0; v < 16; v++) s += sres[v];
    scores[n1] = s * (1.f / 16.f);
  }
}

// ---------------- bilinear 16x upsample [8,32,32] -> [8,512,512] -----------
__global__ __launch_bounds__(256) void upsample_kernel(
    const float* __restrict__ spatch, float* __restrict__ out) {
  int idx = blockIdx.x * 256 + threadIdx.x;
  if (idx >= NN1 * 512 * 512) return;
  int x = idx & 511;
  int y = (idx >> 9) & 511;
  int n = idx >> 18;
  float sx = (x + 0.5f) * 0.0625f - 0.5f;
  float sy = (y + 0.5f) * 0.0625f - 0.5f;
  int x0 = (int)floorf(sx); float wx = sx - (float)x0;
  int y0 = (int)floorf(sy); float wy = sy - (float)y0;
  int x1 = min(x0 + 1, 31); x0 = max(x0, 0);
  int y1 = min(y0 + 1, 31); y0 = max(y0, 0);
  const float* s = spatch + n * PP;
  float v00 = s[y0 * 32 + x0], v01 = s[y0 * 32 + x1];
  float v10 = s[y1 * 32 + x0], v11 = s[y1 * 32 + x1];
  float v = (1.f - wy) * ((1.f - wx) * v00 + wx * v01) +
            wy * ((1.f - wx) * v10 + wx * v11);
  out[idx] = v;
}

extern "C" void kernel_launch(void* const* d_in, const int* in_sizes, int n_in,
                              void* d_out, int out_size, void* d_ws, size_t ws_size,
                              hipStream_t stream) {
  const float* feats  = (const float*)d_in[0];
  const float* nfeats = (const float*)d_in[1];
  const float* mask   = (const float*)d_in[2];
  float* out = (float*)d_out;

  bf16* Abf = (bf16*)d_ws;                                     // 2*8192*768 bf16
  bf16* Bbf = Abf + (size_t)NLAY * MROWS * DD;                 // same size
  float* partials = (float*)(Bbf + (size_t)NLAY * MROWS * DD); // [2][32][8192] f32
  float* spatch   = partials + (size_t)NLAY * NCT * MROWS;     // [8][1024] f32

  normalize_kernel<<<(2 * NLAY * MROWS) / 4, 256, 0, stream>>>(feats, nfeats, Abf, Bbf);

  gemm_max_kernel<<<NCT * (MROWS / BM) * NLAY, 512, 0, stream>>>(Abf, Bbf, partials);

  reduce_kernel<<<NN1, 1024, 0, stream>>>(partials, mask, out, spatch);

  upsample_kernel<<<(NN1 * 512 * 512) / 256, 256, 0, stream>>>(spatch, out + 8);
}